// Round 6
// baseline (217.559 us; speedup 1.0000x reference)
//
#include <hip/hip_runtime.h>

#define B_  8
#define C_  256
#define O_  256
#define H_  56
#define W_  56
#define HW_ 3136
#define KK_ 9
#define CK_ 2304   // C_*KK_
#define NKC 72     // K-chunks of 32

typedef __bf16    bf16x8 __attribute__((ext_vector_type(8)));
typedef float     f32x4  __attribute__((ext_vector_type(4)));

// XOR chunk swizzle: logical 16B-chunk q of row r stored at q ^ swz4(r).
__device__ __forceinline__ int swz4(int r) { return (r & 3) ^ ((r >> 2) & 3); }

__device__ __forceinline__ float blo(unsigned u) {
    return __builtin_bit_cast(float, u << 16);
}
__device__ __forceinline__ float bhi(unsigned u) {
    return __builtin_bit_cast(float, u & 0xffff0000u);
}
__device__ __forceinline__ unsigned pkbf(float lo, float hi) {
    unsigned short a = __builtin_bit_cast(unsigned short, (__bf16)lo);
    unsigned short b = __builtin_bit_cast(unsigned short, (__bf16)hi);
    return (unsigned)a | ((unsigned)b << 16);
}

__device__ __forceinline__ uint4 bilin4(uint4 c00, uint4 c01, uint4 c10, uint4 c11,
                                        float4 wg) {
    uint4 o;
    float lo_, hi_;
    lo_ = wg.x*blo(c00.x) + wg.y*blo(c01.x) + wg.z*blo(c10.x) + wg.w*blo(c11.x);
    hi_ = wg.x*bhi(c00.x) + wg.y*bhi(c01.x) + wg.z*bhi(c10.x) + wg.w*bhi(c11.x);
    o.x = pkbf(lo_, hi_);
    lo_ = wg.x*blo(c00.y) + wg.y*blo(c01.y) + wg.z*blo(c10.y) + wg.w*blo(c11.y);
    hi_ = wg.x*bhi(c00.y) + wg.y*bhi(c01.y) + wg.z*bhi(c10.y) + wg.w*bhi(c11.y);
    o.y = pkbf(lo_, hi_);
    lo_ = wg.x*blo(c00.z) + wg.y*blo(c01.z) + wg.z*blo(c10.z) + wg.w*blo(c11.z);
    hi_ = wg.x*bhi(c00.z) + wg.y*bhi(c01.z) + wg.z*bhi(c10.z) + wg.w*bhi(c11.z);
    o.z = pkbf(lo_, hi_);
    lo_ = wg.x*blo(c00.w) + wg.y*blo(c01.w) + wg.z*blo(c10.w) + wg.w*blo(c11.w);
    hi_ = wg.x*bhi(c00.w) + wg.y*bhi(c01.w) + wg.z*bhi(c10.w) + wg.w*bhi(c11.w);
    o.w = pkbf(lo_, hi_);
    return o;
}

// ---------------------------------------------------------------------------
// Kernel 1: wA[kc][m=256][32] bf16, tap-major K (gk=kc*32+kl -> tap=gk>>8,
// c=gk&255), XOR chunk swizzle baked into the global image. 1.18 MB.
// ---------------------------------------------------------------------------
__global__ __launch_bounds__(256) void k_buildA(const float* __restrict__ w,
                                                unsigned short* __restrict__ wA) {
    int d  = blockIdx.x * 256 + threadIdx.x;   // exact 2304*256
    int kc = d >> 13;
    int rd = d & 8191;
    int m  = rd >> 5;
    int pos = rd & 31;
    int q  = (pos >> 3) ^ swz4(m);
    int kl = q * 8 + (pos & 7);
    int gk = kc * 32 + kl;
    int tap = gk >> 8, c = gk & 255;
    __bf16 v = (__bf16)w[m * CK_ + c * KK_ + tap];
    wA[d] = __builtin_bit_cast(unsigned short, v);
}

// ---------------------------------------------------------------------------
// Kernel 2: x NCHW f32 -> xT NHWC bf16 (12.85 MB).
// ---------------------------------------------------------------------------
__global__ __launch_bounds__(256) void k_transx(const float* __restrict__ x,
                                                unsigned short* __restrict__ xT) {
    __shared__ float s[64][65];
    int bt   = blockIdx.x;            // 8 * 49 * 4
    int c64  = bt & 3;
    int hw64 = (bt >> 2) % 49;
    int b    = bt / 196;
    int tx = threadIdx.x & 63;
    int ty = threadIdx.x >> 6;
#pragma unroll
    for (int i = 0; i < 16; ++i)
        s[i * 4 + ty][tx] =
            x[((size_t)(b * 256 + c64 * 64 + i * 4 + ty)) * HW_ + hw64 * 64 + tx];
    __syncthreads();
#pragma unroll
    for (int i = 0; i < 16; ++i) {
        float v = s[tx][i * 4 + ty];
        xT[((size_t)b * HW_ + hw64 * 64 + i * 4 + ty) * 256 + c64 * 64 + tx] =
            __builtin_bit_cast(unsigned short, (__bf16)v);
    }
}

// ---------------------------------------------------------------------------
// Kernel 3a: offset conv partials. XCD-image swizzle keeps each image's x
// slice (3.2 MB) in one XCD's L2.
// ---------------------------------------------------------------------------
__global__ __launch_bounds__(512) void k_offc1(const float* __restrict__ x,
                                               const float* __restrict__ w_off,
                                               float* __restrict__ part) {
    __shared__ float partial[8][64][18];      // 36864 B
    int t  = threadIdx.x;
    int p  = t & 63;
    int cg = __builtin_amdgcn_readfirstlane(t >> 6);
    int orig = blockIdx.x;                    // 1568 = 8 XCD-chunks * 196
    int blk  = (orig & 7) * 196 + (orig >> 3);
    int sl   = blk & 3;
    int un   = blk >> 2;
    int b    = un / 49;
    int pos0 = (un % 49) * 64;
    int pos  = pos0 + p;
    int h = pos / W_;
    int w = pos % W_;
    const float* xb = x + (size_t)b * C_ * HW_;

    float acc[18];
#pragma unroll
    for (int i = 0; i < 18; ++i) acc[i] = 0.f;

    for (int cc = 0; cc < 8; ++cc) {
        int c = sl * 64 + cg * 8 + cc;
        const float* xp = xb + c * HW_;
        float v[9];
#pragma unroll
        for (int dh = -1; dh <= 1; ++dh)
#pragma unroll
            for (int dw = -1; dw <= 1; ++dw) {
                int hh = h + dh, ww = w + dw;
                bool ok = (hh >= 0) & (hh < H_) & (ww >= 0) & (ww < W_);
                v[(dh + 1) * 3 + dw + 1] = ok ? xp[hh * W_ + ww] : 0.f;
            }
        const float* wc = w_off + c * KK_;
#pragma unroll
        for (int oc = 0; oc < 18; ++oc) {
            const float* wr = wc + oc * CK_;  // wave-uniform -> s_load
#pragma unroll
            for (int k = 0; k < KK_; ++k)
                acc[oc] = fmaf(v[k], wr[k], acc[oc]);
        }
    }
#pragma unroll
    for (int oc = 0; oc < 18; ++oc) partial[cg][p][oc] = acc[oc];
    __syncthreads();

    float* po = part + (size_t)sl * (B_ * 18 * HW_);
    for (int e = t; e < 64 * 18; e += 512) {
        int oc = e >> 6;
        int pp = e & 63;
        float s = 0.f;
#pragma unroll
        for (int g = 0; g < 8; ++g) s += partial[g][pp][oc];
        po[((size_t)b * 18 + oc) * HW_ + pos0 + pp] = s;
    }
}

// ---------------------------------------------------------------------------
// Kernel 3b: sum 4 slices + bias -> off.
// ---------------------------------------------------------------------------
__global__ __launch_bounds__(256) void k_offc2(const float* __restrict__ part,
                                               const float* __restrict__ b_off,
                                               float* __restrict__ off) {
    int i = blockIdx.x * 256 + threadIdx.x;   // exact 451584
    const int NP = B_ * 18 * HW_;
    int oc = (i / HW_) % 18;
    off[i] = part[i] + part[i + NP] + part[i + 2 * NP] + part[i + 3 * NP]
           + b_off[oc];
}

// ---------------------------------------------------------------------------
// Kernel 4 (FUSED gather+GEMM), v5: A-operand LDS round-trip ELIMINATED.
// r4/r5 analysis: kernel was LDS-BW-bound (~104-136 KB/CU/stage ~= the
// observed 1300 cy/stage; occupancy doubling changed nothing). wA is
// L2-resident and identical for all blocks, and the swizzled image makes a
// wave's 4 A-fragments a bijective cover of a contiguous 1 KB region ->
// load af[4] global->reg (coalesced dwordx4), double-buffered one stage
// ahead (register parity, like corners). s_a / async16 / manual vmcnt all
// deleted; compiler tracks reg-load waits exactly. LDS now carries only B
// (4 KB write + 16 KB read per stage). 4 waves, wave tile 64x64, acc[4][4].
// LDS 26.6 KB; launch_bounds(256,3) -> 3 waves/SIMD target.
// ---------------------------------------------------------------------------
template<bool ISSUEC, bool ISSUEA, bool PROD, bool RELID, bool RELWG>
__device__ __forceinline__ void fstage(
    int s, int chNext,
    const char* xb, const char* gA0,
    __bf16 (*s_b)[2048],
    int (*s_id)[64][4], float (*s_w)[64][4],
    int4& id, float4& wg,
    uint4 (&cUse)[4], uint4 (&cFill)[4],
    bf16x8 (&afUse)[4], bf16x8 (&afFill)[4],
    int aoffBase,
    int n, int tc, int sc, int lid, int quad, int swz,
    f32x4 (&acc)[4][4]) {

    if (RELID) {                        // table for corners of B(s+2)
        id = *(const int4*)s_id[(s + 2) >> 3][n];
    }
    if (RELWG) {                        // table for B(s+1)
        wg = *(const float4*)s_w[(s + 1) >> 3][n];
    }
    if (ISSUEC) {                       // corners for B(s+2), used next stage
        const char* p = xb + chNext * 64 + tc * 16;
        cFill[0] = *(const uint4*)(p + id.x);
        cFill[1] = *(const uint4*)(p + id.y);
        cFill[2] = *(const uint4*)(p + id.z);
        cFill[3] = *(const uint4*)(p + id.w);
    }
    if (ISSUEA) {                       // A fragments for stage s+1
        const char* ga = gA0 + (size_t)(s + 1) * 16384 + aoffBase;
        afFill[0] = *(const bf16x8*)(ga);
        afFill[1] = *(const bf16x8*)(ga + 1024);
        afFill[2] = *(const bf16x8*)(ga + 2048);
        afFill[3] = *(const bf16x8*)(ga + 3072);
    }

    const bf16x8* pb = (const bf16x8*)s_b[s & 1];
    bf16x8 bv[4];
#pragma unroll
    for (int ni = 0; ni < 4; ++ni)
        bv[ni] = pb[(ni * 16 + lid) * 4 + (quad ^ swz)];

    __builtin_amdgcn_s_setprio(1);
#pragma unroll
    for (int mi = 0; mi < 4; ++mi)
#pragma unroll
        for (int ni = 0; ni < 4; ++ni)
            acc[mi][ni] = __builtin_amdgcn_mfma_f32_16x16x32_bf16(
                afUse[mi], bv[ni], acc[mi][ni], 0, 0, 0);
    __builtin_amdgcn_s_setprio(0);

    if (PROD) {                         // B(s+1) from corners issued at s-1
        uint4 o = bilin4(cUse[0], cUse[1], cUse[2], cUse[3], wg);
        *(uint4*)((char*)s_b[(s & 1) ^ 1] + n * 64 + sc * 16) = o;
    }
    asm volatile("s_waitcnt lgkmcnt(0)" ::: "memory");
    __builtin_amdgcn_s_barrier();
    __builtin_amdgcn_sched_barrier(0);
}

__global__ __launch_bounds__(256, 3) void k_fused(
    const unsigned short* __restrict__ xT,
    const float* __restrict__ off,
    const __bf16* __restrict__ wA,
    const float* __restrict__ b_dcn,
    float* __restrict__ out) {

    __shared__ __bf16 s_b[2][2048];       //  8 KB: B kc-tile  64n x 32k
    __shared__ int    s_id[KK_][64][4];   //  9 KB
    __shared__ float  s_w [KK_][64][4];   //  9 KB

    int bid  = blockIdx.x;                // 392 = 8 XCDs * 49
    int g    = (bid & 7) * 49 + (bid >> 3);   // image == XCD
    int b    = g / 49;
    int pos0 = (g % 49) * 64;
    int t    = threadIdx.x;
    int lane = t & 63;
    int wv   = t >> 6;                    // 4 waves, 64 M-rows each
    int lid  = lane & 15;
    int quad = lane >> 4;
    int swz  = swz4(lid);

    // --- bilinear tables (byte offsets into NHWC plane, 4 weights) ---
    for (int e = t; e < KK_ * 64; e += 256) {
        int k = e >> 6, n = e & 63;
        int pos = pos0 + n;
        int h = pos / W_, w = pos % W_;
        float dy = off[((size_t)b * 18 + 2 * k) * HW_ + pos];
        float dx = off[((size_t)b * 18 + 2 * k + 1) * HW_ + pos];
        float py = (float)(h + k / 3 - 1) + dy;
        float px = (float)(w + k % 3 - 1) + dx;
        float y0f = floorf(py), x0f = floorf(px);
        float fy = py - y0f, fx = px - x0f;
        int y0 = (int)y0f, x0 = (int)x0f;
        int y1 = y0 + 1,   x1 = x0 + 1;
        float oy0 = (y0 >= 0 && y0 < H_) ? 1.f : 0.f;
        float oy1 = (y1 >= 0 && y1 < H_) ? 1.f : 0.f;
        float ox0 = (x0 >= 0 && x0 < W_) ? 1.f : 0.f;
        float ox1 = (x1 >= 0 && x1 < W_) ? 1.f : 0.f;
        int y0c = min(max(y0, 0), H_ - 1), y1c = min(max(y1, 0), H_ - 1);
        int x0c = min(max(x0, 0), W_ - 1), x1c = min(max(x1, 0), W_ - 1);
        s_id[k][n][0] = (y0c * W_ + x0c) * 512;   // 256 ch * 2 B
        s_id[k][n][1] = (y0c * W_ + x1c) * 512;
        s_id[k][n][2] = (y1c * W_ + x0c) * 512;
        s_id[k][n][3] = (y1c * W_ + x1c) * 512;
        s_w[k][n][0] = (1.f - fy) * (1.f - fx) * oy0 * ox0;
        s_w[k][n][1] = (1.f - fy) * fx         * oy0 * ox1;
        s_w[k][n][2] = fy * (1.f - fx)         * oy1 * ox0;
        s_w[k][n][3] = fy * fx                 * oy1 * ox1;
    }
    __syncthreads();

    int n  = t >> 2;                      // 64 positions
    int tc = t & 3;                       // 16B chunk within 64B k-row
    int sc = tc ^ swz4(n);
    const char* xb  = (const char*)(xT + (size_t)b * HW_ * 256);
    const char* gA0 = (const char*)wA;
    // per-lane A-fragment byte offset within a kc-slice (16 KB):
    // row (wv*64 + mi*16 + lid) * 64B + swizzled chunk (quad^swz)*16B
    int aoffBase = (wv * 64 + lid) * 64 + (quad ^ swz) * 16;

    f32x4 acc[4][4];
#pragma unroll
    for (int mi = 0; mi < 4; ++mi)
#pragma unroll
        for (int ni = 0; ni < 4; ++ni)
            acc[mi][ni] = (f32x4)(0.f);

    int4   id = *(const int4*)s_id[0][n];
    float4 wg = *(const float4*)s_w[0][n];
    uint4  cA[4], cB[4];
    bf16x8 afA[4], afB[4];

    // ---- prologue: B(0) built in-reg; af(0) loaded; corners(B(1)) issued ----
    {
        const char* p0 = xb + tc * 16;            // ch-block 0
        uint4 c0[4];
        c0[0] = *(const uint4*)(p0 + id.x);
        c0[1] = *(const uint4*)(p0 + id.y);
        c0[2] = *(const uint4*)(p0 + id.z);
        c0[3] = *(const uint4*)(p0 + id.w);
        const char* ga = gA0 + aoffBase;          // af(0)
        afA[0] = *(const bf16x8*)(ga);
        afA[1] = *(const bf16x8*)(ga + 1024);
        afA[2] = *(const bf16x8*)(ga + 2048);
        afA[3] = *(const bf16x8*)(ga + 3072);
        const char* p1 = xb + 64 + tc * 16;       // corners for B(1), ch 1
        cA[0] = *(const uint4*)(p1 + id.x);
        cA[1] = *(const uint4*)(p1 + id.y);
        cA[2] = *(const uint4*)(p1 + id.z);
        cA[3] = *(const uint4*)(p1 + id.w);
        uint4 o = bilin4(c0[0], c0[1], c0[2], c0[3], wg);
        *(uint4*)((char*)s_b[0] + n * 64 + sc * 16) = o;
    }
    asm volatile("s_waitcnt lgkmcnt(0)" ::: "memory");
    __builtin_amdgcn_s_barrier();
    __builtin_amdgcn_sched_barrier(0);

    // ---- main: 8 full tap-blocks (s = 0..63) ----
    // stage i: Use = set[i&1], Fill = set[(i+1)&1] (both corners and af)
    for (int tap = 0; tap < 8; ++tap) {
        int s0 = tap * 8;
        fstage<true, true, true, false, false>(s0 + 0, 2, xb, gA0, s_b, s_id, s_w, id, wg, cA, cB, afA, afB, aoffBase, n, tc, sc, lid, quad, swz, acc);
        fstage<true, true, true, false, false>(s0 + 1, 3, xb, gA0, s_b, s_id, s_w, id, wg, cB, cA, afB, afA, aoffBase, n, tc, sc, lid, quad, swz, acc);
        fstage<true, true, true, false, false>(s0 + 2, 4, xb, gA0, s_b, s_id, s_w, id, wg, cA, cB, afA, afB, aoffBase, n, tc, sc, lid, quad, swz, acc);
        fstage<true, true, true, false, false>(s0 + 3, 5, xb, gA0, s_b, s_id, s_w, id, wg, cB, cA, afB, afA, aoffBase, n, tc, sc, lid, quad, swz, acc);
        fstage<true, true, true, false, false>(s0 + 4, 6, xb, gA0, s_b, s_id, s_w, id, wg, cA, cB, afA, afB, aoffBase, n, tc, sc, lid, quad, swz, acc);
        fstage<true, true, true, false, false>(s0 + 5, 7, xb, gA0, s_b, s_id, s_w, id, wg, cB, cA, afB, afA, aoffBase, n, tc, sc, lid, quad, swz, acc);
        fstage<true, true, true, true,  false>(s0 + 6, 0, xb, gA0, s_b, s_id, s_w, id, wg, cA, cB, afA, afB, aoffBase, n, tc, sc, lid, quad, swz, acc);
        fstage<true, true, true, false, true >(s0 + 7, 1, xb, gA0, s_b, s_id, s_w, id, wg, cB, cA, afB, afA, aoffBase, n, tc, sc, lid, quad, swz, acc);
    }
    // ---- tail tap-block (s = 64..71, tap 8) ----
    fstage<true,  true,  true,  false, false>(64, 2, xb, gA0, s_b, s_id, s_w, id, wg, cA, cB, afA, afB, aoffBase, n, tc, sc, lid, quad, swz, acc);
    fstage<true,  true,  true,  false, false>(65, 3, xb, gA0, s_b, s_id, s_w, id, wg, cB, cA, afB, afA, aoffBase, n, tc, sc, lid, quad, swz, acc);
    fstage<true,  true,  true,  false, false>(66, 4, xb, gA0, s_b, s_id, s_w, id, wg, cA, cB, afA, afB, aoffBase, n, tc, sc, lid, quad, swz, acc);
    fstage<true,  true,  true,  false, false>(67, 5, xb, gA0, s_b, s_id, s_w, id, wg, cB, cA, afB, afA, aoffBase, n, tc, sc, lid, quad, swz, acc);
    fstage<true,  true,  true,  false, false>(68, 6, xb, gA0, s_b, s_id, s_w, id, wg, cA, cB, afA, afB, aoffBase, n, tc, sc, lid, quad, swz, acc);
    fstage<true,  true,  true,  false, false>(69, 7, xb, gA0, s_b, s_id, s_w, id, wg, cB, cA, afB, afA, aoffBase, n, tc, sc, lid, quad, swz, acc);
    fstage<false, true,  true,  false, false>(70, 0, xb, gA0, s_b, s_id, s_w, id, wg, cA, cB, afA, afB, aoffBase, n, tc, sc, lid, quad, swz, acc);
    fstage<false, false, false, false, false>(71, 1, xb, gA0, s_b, s_id, s_w, id, wg, cB, cA, afB, afA, aoffBase, n, tc, sc, lid, quad, swz, acc);

    // ---- epilogue: bias + store. D: col(n)=lane&15, row(m)=quad*4+reg ----
#pragma unroll
    for (int mi = 0; mi < 4; ++mi) {
#pragma unroll
        for (int r = 0; r < 4; ++r) {
            int m = wv * 64 + mi * 16 + quad * 4 + r;
            float bias = b_dcn[m];
            float* po = out + ((size_t)b * O_ + m) * HW_ + pos0 + lid;
#pragma unroll
            for (int ni = 0; ni < 4; ++ni)
                po[ni * 16] = acc[mi][ni][r] + bias;
        }
    }
}

extern "C" void kernel_launch(void* const* d_in, const int* in_sizes, int n_in,
                              void* d_out, int out_size, void* d_ws, size_t ws_size,
                              hipStream_t stream) {
    const float* x     = (const float*)d_in[0];
    const float* w_off = (const float*)d_in[1];
    const float* b_off = (const float*)d_in[2];
    const float* w_dcn = (const float*)d_in[3];
    const float* b_dcn = (const float*)d_in[4];
    float* out = (float*)d_out;

    // ws: off 1.81 | wA 1.18 | xT 12.85 | part 7.23 MB
    const size_t offBytes  = (size_t)451584 * 4;
    const size_t wABytes   = (size_t)589824 * 2;
    const size_t xTBytes   = (size_t)B_ * HW_ * 256 * 2;
    float*          off  = (float*)d_ws;
    unsigned short* wA   = (unsigned short*)((char*)d_ws + offBytes);
    unsigned short* xT   = (unsigned short*)((char*)d_ws + offBytes + wABytes);
    float*          part = (float*)((char*)d_ws + offBytes + wABytes + xTBytes);

    k_buildA <<<2304, 256, 0, stream>>>(w_dcn, wA);
    k_transx <<<1568, 256, 0, stream>>>(x, xT);
    k_offc1  <<<1568, 512, 0, stream>>>(x, w_off, part);
    k_offc2  <<<1764, 256, 0, stream>>>(part, b_off, off);
    k_fused  <<<392,  256, 0, stream>>>(xT, off, (const __bf16*)wA, b_dcn, out);
}

// Round 7
// 193.807 us; speedup vs baseline: 1.1226x; 1.1226x over previous
//
#include <hip/hip_runtime.h>

#define B_  8
#define C_  256
#define O_  256
#define H_  56
#define W_  56
#define HW_ 3136
#define KK_ 9
#define CK_ 2304   // C_*KK_
#define NKC 72     // K-chunks of 32

typedef __bf16    bf16x8 __attribute__((ext_vector_type(8)));
typedef float     f32x4  __attribute__((ext_vector_type(4)));

// XOR chunk swizzle: logical 16B-chunk q of row r stored at q ^ swz4(r).
__device__ __forceinline__ int swz4(int r) { return (r & 3) ^ ((r >> 2) & 3); }

__device__ __forceinline__ float blo(unsigned u) {
    return __builtin_bit_cast(float, u << 16);
}
__device__ __forceinline__ float bhi(unsigned u) {
    return __builtin_bit_cast(float, u & 0xffff0000u);
}
__device__ __forceinline__ unsigned pkbf(float lo, float hi) {
    unsigned short a = __builtin_bit_cast(unsigned short, (__bf16)lo);
    unsigned short b = __builtin_bit_cast(unsigned short, (__bf16)hi);
    return (unsigned)a | ((unsigned)b << 16);
}

__device__ __forceinline__ uint4 bilin4(uint4 c00, uint4 c01, uint4 c10, uint4 c11,
                                        float4 wg) {
    uint4 o;
    float lo_, hi_;
    lo_ = wg.x*blo(c00.x) + wg.y*blo(c01.x) + wg.z*blo(c10.x) + wg.w*blo(c11.x);
    hi_ = wg.x*bhi(c00.x) + wg.y*bhi(c01.x) + wg.z*bhi(c10.x) + wg.w*bhi(c11.x);
    o.x = pkbf(lo_, hi_);
    lo_ = wg.x*blo(c00.y) + wg.y*blo(c01.y) + wg.z*blo(c10.y) + wg.w*blo(c11.y);
    hi_ = wg.x*bhi(c00.y) + wg.y*bhi(c01.y) + wg.z*bhi(c10.y) + wg.w*bhi(c11.y);
    o.y = pkbf(lo_, hi_);
    lo_ = wg.x*blo(c00.z) + wg.y*blo(c01.z) + wg.z*blo(c10.z) + wg.w*blo(c11.z);
    hi_ = wg.x*bhi(c00.z) + wg.y*bhi(c01.z) + wg.z*bhi(c10.z) + wg.w*bhi(c11.z);
    o.z = pkbf(lo_, hi_);
    lo_ = wg.x*blo(c00.w) + wg.y*blo(c01.w) + wg.z*blo(c10.w) + wg.w*blo(c11.w);
    hi_ = wg.x*bhi(c00.w) + wg.y*bhi(c01.w) + wg.z*bhi(c10.w) + wg.w*bhi(c11.w);
    o.w = pkbf(lo_, hi_);
    return o;
}

// ---------------------------------------------------------------------------
// Kernel 1: wA[kc][m=256][32] bf16, tap-major K (gk=kc*32+kl -> tap=gk>>8,
// c=gk&255), XOR chunk swizzle baked into the global image. 1.18 MB.
// ---------------------------------------------------------------------------
__global__ __launch_bounds__(256) void k_buildA(const float* __restrict__ w,
                                                unsigned short* __restrict__ wA) {
    int d  = blockIdx.x * 256 + threadIdx.x;   // exact 2304*256
    int kc = d >> 13;
    int rd = d & 8191;
    int m  = rd >> 5;
    int pos = rd & 31;
    int q  = (pos >> 3) ^ swz4(m);
    int kl = q * 8 + (pos & 7);
    int gk = kc * 32 + kl;
    int tap = gk >> 8, c = gk & 255;
    __bf16 v = (__bf16)w[m * CK_ + c * KK_ + tap];
    wA[d] = __builtin_bit_cast(unsigned short, v);
}

// ---------------------------------------------------------------------------
// Kernel 2: x NCHW f32 -> xT NHWC bf16 (12.85 MB).
// ---------------------------------------------------------------------------
__global__ __launch_bounds__(256) void k_transx(const float* __restrict__ x,
                                                unsigned short* __restrict__ xT) {
    __shared__ float s[64][65];
    int bt   = blockIdx.x;            // 8 * 49 * 4
    int c64  = bt & 3;
    int hw64 = (bt >> 2) % 49;
    int b    = bt / 196;
    int tx = threadIdx.x & 63;
    int ty = threadIdx.x >> 6;
#pragma unroll
    for (int i = 0; i < 16; ++i)
        s[i * 4 + ty][tx] =
            x[((size_t)(b * 256 + c64 * 64 + i * 4 + ty)) * HW_ + hw64 * 64 + tx];
    __syncthreads();
#pragma unroll
    for (int i = 0; i < 16; ++i) {
        float v = s[tx][i * 4 + ty];
        xT[((size_t)b * HW_ + hw64 * 64 + i * 4 + ty) * 256 + c64 * 64 + tx] =
            __builtin_bit_cast(unsigned short, (__bf16)v);
    }
}

// ---------------------------------------------------------------------------
// Kernel 3a: offset conv partials. XCD-image swizzle keeps each image's x
// slice (3.2 MB) in one XCD's L2.
// ---------------------------------------------------------------------------
__global__ __launch_bounds__(512) void k_offc1(const float* __restrict__ x,
                                               const float* __restrict__ w_off,
                                               float* __restrict__ part) {
    __shared__ float partial[8][64][18];      // 36864 B
    int t  = threadIdx.x;
    int p  = t & 63;
    int cg = __builtin_amdgcn_readfirstlane(t >> 6);
    int orig = blockIdx.x;                    // 1568 = 8 XCD-chunks * 196
    int blk  = (orig & 7) * 196 + (orig >> 3);
    int sl   = blk & 3;
    int un   = blk >> 2;
    int b    = un / 49;
    int pos0 = (un % 49) * 64;
    int pos  = pos0 + p;
    int h = pos / W_;
    int w = pos % W_;
    const float* xb = x + (size_t)b * C_ * HW_;

    float acc[18];
#pragma unroll
    for (int i = 0; i < 18; ++i) acc[i] = 0.f;

    for (int cc = 0; cc < 8; ++cc) {
        int c = sl * 64 + cg * 8 + cc;
        const float* xp = xb + c * HW_;
        float v[9];
#pragma unroll
        for (int dh = -1; dh <= 1; ++dh)
#pragma unroll
            for (int dw = -1; dw <= 1; ++dw) {
                int hh = h + dh, ww = w + dw;
                bool ok = (hh >= 0) & (hh < H_) & (ww >= 0) & (ww < W_);
                v[(dh + 1) * 3 + dw + 1] = ok ? xp[hh * W_ + ww] : 0.f;
            }
        const float* wc = w_off + c * KK_;
#pragma unroll
        for (int oc = 0; oc < 18; ++oc) {
            const float* wr = wc + oc * CK_;  // wave-uniform -> s_load
#pragma unroll
            for (int k = 0; k < KK_; ++k)
                acc[oc] = fmaf(v[k], wr[k], acc[oc]);
        }
    }
#pragma unroll
    for (int oc = 0; oc < 18; ++oc) partial[cg][p][oc] = acc[oc];
    __syncthreads();

    float* po = part + (size_t)sl * (B_ * 18 * HW_);
    for (int e = t; e < 64 * 18; e += 512) {
        int oc = e >> 6;
        int pp = e & 63;
        float s = 0.f;
#pragma unroll
        for (int g = 0; g < 8; ++g) s += partial[g][pp][oc];
        po[((size_t)b * 18 + oc) * HW_ + pos0 + pp] = s;
    }
}

// ---------------------------------------------------------------------------
// Kernel 3b: sum 4 slices + bias -> off.
// ---------------------------------------------------------------------------
__global__ __launch_bounds__(256) void k_offc2(const float* __restrict__ part,
                                               const float* __restrict__ b_off,
                                               float* __restrict__ off) {
    int i = blockIdx.x * 256 + threadIdx.x;   // exact 451584
    const int NP = B_ * 18 * HW_;
    int oc = (i / HW_) % 18;
    off[i] = part[i] + part[i + NP] + part[i + 2 * NP] + part[i + 3 * NP]
           + b_off[oc];
}

// ---------------------------------------------------------------------------
// Kernel 4 (FUSED gather+GEMM), v7 = v6's A-in-registers dataflow with the
// spill FIXED (v6: launch_bounds(256,3) capped VGPR at ~170 < ~190 live ->
// scratch; WRITE_SIZE 25->102 MB was the giveaway).
//   1. Corners SINGLE-buffered (round-4-verified dataflow: issue at stage
//      top for B(s+1), consume after the MFMA cluster) -> -16 VGPR.
//   2. launch_bounds(256,2) -> 256-reg cap, no spill (occupancy is
//      grid-limited anyway).
// A: af[4] global->reg from the L2-resident swizzled wA image, double-
//    buffered one stage ahead (reg parity). No LDS for A at all.
// B: 4 uint4 corner loads -> bilinear -> swizzled ds_write_b128, 2-stage
//    LDS double buffer. LDS/stage: 4 KB write + 16 KB read (was 52 KB).
// LDS total 26.6 KB. 4 waves, wave tile 64x64, acc[4][4] (AGPRs).
// ---------------------------------------------------------------------------
template<bool ISSUEC, bool ISSUEA, bool PROD, bool RELOAD>
__device__ __forceinline__ void fstage(
    int s, int chNext,
    const char* xb, const char* gA0,
    __bf16 (*s_b)[2048],
    int (*s_id)[64][4], float (*s_w)[64][4],
    int4& id, float4& wg,
    bf16x8 (&afUse)[4], bf16x8 (&afFill)[4],
    int aoffBase,
    int n, int tc, int sc, int lid, int quad, int swz,
    f32x4 (&acc)[4][4]) {

    if (RELOAD) {                       // tables for tap (s+1)>>3: corners
        id = *(const int4*)s_id[(s + 1) >> 3][n];   // issued THIS stage and
        wg = *(const float4*)s_w[(s + 1) >> 3][n];  // bilinear THIS stage
    }
    uint4 c0, c1, c2, c3;
    if (ISSUEC) {                       // corners for B(s+1), used after MFMA
        const char* p = xb + chNext * 64 + tc * 16;
        c0 = *(const uint4*)(p + id.x);
        c1 = *(const uint4*)(p + id.y);
        c2 = *(const uint4*)(p + id.z);
        c3 = *(const uint4*)(p + id.w);
    }
    if (ISSUEA) {                       // A fragments for stage s+1
        const char* ga = gA0 + (size_t)(s + 1) * 16384 + aoffBase;
        afFill[0] = *(const bf16x8*)(ga);
        afFill[1] = *(const bf16x8*)(ga + 1024);
        afFill[2] = *(const bf16x8*)(ga + 2048);
        afFill[3] = *(const bf16x8*)(ga + 3072);
    }

    const bf16x8* pb = (const bf16x8*)s_b[s & 1];
    bf16x8 bv[4];
#pragma unroll
    for (int ni = 0; ni < 4; ++ni)
        bv[ni] = pb[(ni * 16 + lid) * 4 + (quad ^ swz)];

    __builtin_amdgcn_s_setprio(1);
#pragma unroll
    for (int mi = 0; mi < 4; ++mi)
#pragma unroll
        for (int ni = 0; ni < 4; ++ni)
            acc[mi][ni] = __builtin_amdgcn_mfma_f32_16x16x32_bf16(
                afUse[mi], bv[ni], acc[mi][ni], 0, 0, 0);
    __builtin_amdgcn_s_setprio(0);

    if (PROD) {                         // B(s+1) from this stage's corners
        uint4 o = bilin4(c0, c1, c2, c3, wg);
        *(uint4*)((char*)s_b[(s & 1) ^ 1] + n * 64 + sc * 16) = o;
    }
    asm volatile("s_waitcnt lgkmcnt(0)" ::: "memory");
    __builtin_amdgcn_s_barrier();
    __builtin_amdgcn_sched_barrier(0);
}

__global__ __launch_bounds__(256, 2) void k_fused(
    const unsigned short* __restrict__ xT,
    const float* __restrict__ off,
    const __bf16* __restrict__ wA,
    const float* __restrict__ b_dcn,
    float* __restrict__ out) {

    __shared__ __bf16 s_b[2][2048];       //  8 KB: B kc-tile  64n x 32k
    __shared__ int    s_id[KK_][64][4];   //  9 KB
    __shared__ float  s_w [KK_][64][4];   //  9 KB

    int bid  = blockIdx.x;                // 392 = 8 XCDs * 49
    int g    = (bid & 7) * 49 + (bid >> 3);   // image == XCD
    int b    = g / 49;
    int pos0 = (g % 49) * 64;
    int t    = threadIdx.x;
    int lane = t & 63;
    int wv   = t >> 6;                    // 4 waves, 64 M-rows each
    int lid  = lane & 15;
    int quad = lane >> 4;
    int swz  = swz4(lid);

    // --- bilinear tables (byte offsets into NHWC plane, 4 weights) ---
    for (int e = t; e < KK_ * 64; e += 256) {
        int k = e >> 6, n = e & 63;
        int pos = pos0 + n;
        int h = pos / W_, w = pos % W_;
        float dy = off[((size_t)b * 18 + 2 * k) * HW_ + pos];
        float dx = off[((size_t)b * 18 + 2 * k + 1) * HW_ + pos];
        float py = (float)(h + k / 3 - 1) + dy;
        float px = (float)(w + k % 3 - 1) + dx;
        float y0f = floorf(py), x0f = floorf(px);
        float fy = py - y0f, fx = px - x0f;
        int y0 = (int)y0f, x0 = (int)x0f;
        int y1 = y0 + 1,   x1 = x0 + 1;
        float oy0 = (y0 >= 0 && y0 < H_) ? 1.f : 0.f;
        float oy1 = (y1 >= 0 && y1 < H_) ? 1.f : 0.f;
        float ox0 = (x0 >= 0 && x0 < W_) ? 1.f : 0.f;
        float ox1 = (x1 >= 0 && x1 < W_) ? 1.f : 0.f;
        int y0c = min(max(y0, 0), H_ - 1), y1c = min(max(y1, 0), H_ - 1);
        int x0c = min(max(x0, 0), W_ - 1), x1c = min(max(x1, 0), W_ - 1);
        s_id[k][n][0] = (y0c * W_ + x0c) * 512;   // 256 ch * 2 B
        s_id[k][n][1] = (y0c * W_ + x1c) * 512;
        s_id[k][n][2] = (y1c * W_ + x0c) * 512;
        s_id[k][n][3] = (y1c * W_ + x1c) * 512;
        s_w[k][n][0] = (1.f - fy) * (1.f - fx) * oy0 * ox0;
        s_w[k][n][1] = (1.f - fy) * fx         * oy0 * ox1;
        s_w[k][n][2] = fy * (1.f - fx)         * oy1 * ox0;
        s_w[k][n][3] = fy * fx                 * oy1 * ox1;
    }
    __syncthreads();

    int n  = t >> 2;                      // 64 positions
    int tc = t & 3;                       // 16B chunk within 64B k-row
    int sc = tc ^ swz4(n);
    const char* xb  = (const char*)(xT + (size_t)b * HW_ * 256);
    const char* gA0 = (const char*)wA;
    // per-lane A-fragment byte offset within a kc-slice (16 KB):
    // row (wv*64 + mi*16 + lid) * 64B + swizzled chunk (quad^swz)*16B
    int aoffBase = (wv * 64 + lid) * 64 + (quad ^ swz) * 16;

    f32x4 acc[4][4];
#pragma unroll
    for (int mi = 0; mi < 4; ++mi)
#pragma unroll
        for (int ni = 0; ni < 4; ++ni)
            acc[mi][ni] = (f32x4)(0.f);

    int4   id = *(const int4*)s_id[0][n];
    float4 wg = *(const float4*)s_w[0][n];
    bf16x8 afA[4], afB[4];

    // ---- prologue: B(0) built in-reg; af(0) loaded ----
    {
        const char* p0 = xb + tc * 16;            // ch-block 0, tap 0
        uint4 c0 = *(const uint4*)(p0 + id.x);
        uint4 c1 = *(const uint4*)(p0 + id.y);
        uint4 c2 = *(const uint4*)(p0 + id.z);
        uint4 c3 = *(const uint4*)(p0 + id.w);
        const char* ga = gA0 + aoffBase;          // af(0)
        afA[0] = *(const bf16x8*)(ga);
        afA[1] = *(const bf16x8*)(ga + 1024);
        afA[2] = *(const bf16x8*)(ga + 2048);
        afA[3] = *(const bf16x8*)(ga + 3072);
        uint4 o = bilin4(c0, c1, c2, c3, wg);
        *(uint4*)((char*)s_b[0] + n * 64 + sc * 16) = o;
    }
    asm volatile("s_waitcnt lgkmcnt(0)" ::: "memory");
    __builtin_amdgcn_s_barrier();
    __builtin_amdgcn_sched_barrier(0);

    // ---- main: 8 full tap-blocks (s = 0..63) ----
    // stage s: afUse = set[s&1], afFill = set[(s+1)&1]; RELOAD at i==7.
    for (int tap = 0; tap < 8; ++tap) {
        int s0 = tap * 8;
        fstage<true, true, true, false>(s0 + 0, 1, xb, gA0, s_b, s_id, s_w, id, wg, afA, afB, aoffBase, n, tc, sc, lid, quad, swz, acc);
        fstage<true, true, true, false>(s0 + 1, 2, xb, gA0, s_b, s_id, s_w, id, wg, afB, afA, aoffBase, n, tc, sc, lid, quad, swz, acc);
        fstage<true, true, true, false>(s0 + 2, 3, xb, gA0, s_b, s_id, s_w, id, wg, afA, afB, aoffBase, n, tc, sc, lid, quad, swz, acc);
        fstage<true, true, true, false>(s0 + 3, 4, xb, gA0, s_b, s_id, s_w, id, wg, afB, afA, aoffBase, n, tc, sc, lid, quad, swz, acc);
        fstage<true, true, true, false>(s0 + 4, 5, xb, gA0, s_b, s_id, s_w, id, wg, afA, afB, aoffBase, n, tc, sc, lid, quad, swz, acc);
        fstage<true, true, true, false>(s0 + 5, 6, xb, gA0, s_b, s_id, s_w, id, wg, afB, afA, aoffBase, n, tc, sc, lid, quad, swz, acc);
        fstage<true, true, true, false>(s0 + 6, 7, xb, gA0, s_b, s_id, s_w, id, wg, afA, afB, aoffBase, n, tc, sc, lid, quad, swz, acc);
        fstage<true, true, true, true >(s0 + 7, 0, xb, gA0, s_b, s_id, s_w, id, wg, afB, afA, aoffBase, n, tc, sc, lid, quad, swz, acc);
    }
    // ---- tail tap-block (s = 64..71, tap 8) ----
    fstage<true,  true,  true,  false>(64, 1, xb, gA0, s_b, s_id, s_w, id, wg, afA, afB, aoffBase, n, tc, sc, lid, quad, swz, acc);
    fstage<true,  true,  true,  false>(65, 2, xb, gA0, s_b, s_id, s_w, id, wg, afB, afA, aoffBase, n, tc, sc, lid, quad, swz, acc);
    fstage<true,  true,  true,  false>(66, 3, xb, gA0, s_b, s_id, s_w, id, wg, afA, afB, aoffBase, n, tc, sc, lid, quad, swz, acc);
    fstage<true,  true,  true,  false>(67, 4, xb, gA0, s_b, s_id, s_w, id, wg, afB, afA, aoffBase, n, tc, sc, lid, quad, swz, acc);
    fstage<true,  true,  true,  false>(68, 5, xb, gA0, s_b, s_id, s_w, id, wg, afA, afB, aoffBase, n, tc, sc, lid, quad, swz, acc);
    fstage<true,  true,  true,  false>(69, 6, xb, gA0, s_b, s_id, s_w, id, wg, afB, afA, aoffBase, n, tc, sc, lid, quad, swz, acc);
    fstage<true,  true,  true,  false>(70, 7, xb, gA0, s_b, s_id, s_w, id, wg, afA, afB, aoffBase, n, tc, sc, lid, quad, swz, acc);
    fstage<false, false, false, false>(71, 0, xb, gA0, s_b, s_id, s_w, id, wg, afB, afA, aoffBase, n, tc, sc, lid, quad, swz, acc);

    // ---- epilogue: bias + store. D: col(n)=lane&15, row(m)=quad*4+reg ----
#pragma unroll
    for (int mi = 0; mi < 4; ++mi) {
#pragma unroll
        for (int r = 0; r < 4; ++r) {
            int m = wv * 64 + mi * 16 + quad * 4 + r;
            float bias = b_dcn[m];
            float* po = out + ((size_t)b * O_ + m) * HW_ + pos0 + lid;
#pragma unroll
            for (int ni = 0; ni < 4; ++ni)
                po[ni * 16] = acc[mi][ni][r] + bias;
        }
    }
}

extern "C" void kernel_launch(void* const* d_in, const int* in_sizes, int n_in,
                              void* d_out, int out_size, void* d_ws, size_t ws_size,
                              hipStream_t stream) {
    const float* x     = (const float*)d_in[0];
    const float* w_off = (const float*)d_in[1];
    const float* b_off = (const float*)d_in[2];
    const float* w_dcn = (const float*)d_in[3];
    const float* b_dcn = (const float*)d_in[4];
    float* out = (float*)d_out;

    // ws: off 1.81 | wA 1.18 | xT 12.85 | part 7.23 MB
    const size_t offBytes  = (size_t)451584 * 4;
    const size_t wABytes   = (size_t)589824 * 2;
    const size_t xTBytes   = (size_t)B_ * HW_ * 256 * 2;
    float*          off  = (float*)d_ws;
    unsigned short* wA   = (unsigned short*)((char*)d_ws + offBytes);
    unsigned short* xT   = (unsigned short*)((char*)d_ws + offBytes + wABytes);
    float*          part = (float*)((char*)d_ws + offBytes + wABytes + xTBytes);

    k_buildA <<<2304, 256, 0, stream>>>(w_dcn, wA);
    k_transx <<<1568, 256, 0, stream>>>(x, xT);
    k_offc1  <<<1568, 512, 0, stream>>>(x, w_off, part);
    k_offc2  <<<1764, 256, 0, stream>>>(part, b_off, off);
    k_fused  <<<392,  256, 0, stream>>>(xT, off, (const __bf16*)wA, b_dcn, out);
}

// Round 8
// 192.317 us; speedup vs baseline: 1.1313x; 1.0077x over previous
//
#include <hip/hip_runtime.h>

#define B_  8
#define C_  256
#define O_  256
#define H_  56
#define W_  56
#define HW_ 3136
#define KK_ 9
#define CK_ 2304   // C_*KK_
#define NKC 72     // K-chunks of 32

typedef __bf16    bf16x8 __attribute__((ext_vector_type(8)));
typedef float     f32x4  __attribute__((ext_vector_type(4)));

// XOR chunk swizzle: logical 16B-chunk q of row r stored at q ^ swz4(r).
__device__ __forceinline__ int swz4(int r) { return (r & 3) ^ ((r >> 2) & 3); }

__device__ __forceinline__ float blo(unsigned u) {
    return __builtin_bit_cast(float, u << 16);
}
__device__ __forceinline__ float bhi(unsigned u) {
    return __builtin_bit_cast(float, u & 0xffff0000u);
}
__device__ __forceinline__ unsigned pkbf(float lo, float hi) {
    unsigned short a = __builtin_bit_cast(unsigned short, (__bf16)lo);
    unsigned short b = __builtin_bit_cast(unsigned short, (__bf16)hi);
    return (unsigned)a | ((unsigned)b << 16);
}

__device__ __forceinline__ uint4 bilin4(uint4 c00, uint4 c01, uint4 c10, uint4 c11,
                                        float4 wg) {
    uint4 o;
    float lo_, hi_;
    lo_ = wg.x*blo(c00.x) + wg.y*blo(c01.x) + wg.z*blo(c10.x) + wg.w*blo(c11.x);
    hi_ = wg.x*bhi(c00.x) + wg.y*bhi(c01.x) + wg.z*bhi(c10.x) + wg.w*bhi(c11.x);
    o.x = pkbf(lo_, hi_);
    lo_ = wg.x*blo(c00.y) + wg.y*blo(c01.y) + wg.z*blo(c10.y) + wg.w*blo(c11.y);
    hi_ = wg.x*bhi(c00.y) + wg.y*bhi(c01.y) + wg.z*bhi(c10.y) + wg.w*bhi(c11.y);
    o.y = pkbf(lo_, hi_);
    lo_ = wg.x*blo(c00.z) + wg.y*blo(c01.z) + wg.z*blo(c10.z) + wg.w*blo(c11.z);
    hi_ = wg.x*bhi(c00.z) + wg.y*bhi(c01.z) + wg.z*bhi(c10.z) + wg.w*bhi(c11.z);
    o.z = pkbf(lo_, hi_);
    lo_ = wg.x*blo(c00.w) + wg.y*blo(c01.w) + wg.z*blo(c10.w) + wg.w*blo(c11.w);
    hi_ = wg.x*bhi(c00.w) + wg.y*bhi(c01.w) + wg.z*bhi(c10.w) + wg.w*bhi(c11.w);
    o.w = pkbf(lo_, hi_);
    return o;
}

// ---------------------------------------------------------------------------
// Kernel 1: wA[kc][m=256][32] bf16, tap-major K (gk=kc*32+kl -> tap=gk>>8,
// c=gk&255), XOR chunk swizzle baked into the global image. 1.18 MB.
// ---------------------------------------------------------------------------
__global__ __launch_bounds__(256) void k_buildA(const float* __restrict__ w,
                                                unsigned short* __restrict__ wA) {
    int d  = blockIdx.x * 256 + threadIdx.x;   // exact 2304*256
    int kc = d >> 13;
    int rd = d & 8191;
    int m  = rd >> 5;
    int pos = rd & 31;
    int q  = (pos >> 3) ^ swz4(m);
    int kl = q * 8 + (pos & 7);
    int gk = kc * 32 + kl;
    int tap = gk >> 8, c = gk & 255;
    __bf16 v = (__bf16)w[m * CK_ + c * KK_ + tap];
    wA[d] = __builtin_bit_cast(unsigned short, v);
}

// ---------------------------------------------------------------------------
// Kernel 2: x NCHW f32 -> xT NHWC bf16 (12.85 MB).
// ---------------------------------------------------------------------------
__global__ __launch_bounds__(256) void k_transx(const float* __restrict__ x,
                                                unsigned short* __restrict__ xT) {
    __shared__ float s[64][65];
    int bt   = blockIdx.x;            // 8 * 49 * 4
    int c64  = bt & 3;
    int hw64 = (bt >> 2) % 49;
    int b    = bt / 196;
    int tx = threadIdx.x & 63;
    int ty = threadIdx.x >> 6;
#pragma unroll
    for (int i = 0; i < 16; ++i)
        s[i * 4 + ty][tx] =
            x[((size_t)(b * 256 + c64 * 64 + i * 4 + ty)) * HW_ + hw64 * 64 + tx];
    __syncthreads();
#pragma unroll
    for (int i = 0; i < 16; ++i) {
        float v = s[tx][i * 4 + ty];
        xT[((size_t)b * HW_ + hw64 * 64 + i * 4 + ty) * 256 + c64 * 64 + tx] =
            __builtin_bit_cast(unsigned short, (__bf16)v);
    }
}

// ---------------------------------------------------------------------------
// Kernel 3 (MERGED offc1+offc2): full 256-channel offset conv per block,
// writes off (+bias) directly. No part round-trip (was 58 MB), no 2nd
// kernel. Grid 392 = 8 XCDs x 49; XCD-image swizzle keeps the x slice
// (3.2 MB) L2-resident. 512 thr = 64 pos x 8 groups of 32 ch; LDS-reduce.
// ---------------------------------------------------------------------------
__global__ __launch_bounds__(512) void k_offc(const float* __restrict__ x,
                                              const float* __restrict__ w_off,
                                              const float* __restrict__ b_off,
                                              float* __restrict__ off) {
    __shared__ float partial[8][64][18];      // 36864 B
    int t  = threadIdx.x;
    int p  = t & 63;
    int cg = __builtin_amdgcn_readfirstlane(t >> 6);
    int bid  = blockIdx.x;                    // 392 = 8 XCDs * 49
    int g    = (bid & 7) * 49 + (bid >> 3);
    int b    = g / 49;
    int pos0 = (g % 49) * 64;
    int pos  = pos0 + p;
    int h = pos / W_;
    int w = pos % W_;
    const float* xb = x + (size_t)b * C_ * HW_;

    float acc[18];
#pragma unroll
    for (int i = 0; i < 18; ++i) acc[i] = 0.f;

    for (int cc = 0; cc < 32; ++cc) {
        int c = cg * 32 + cc;
        const float* xp = xb + c * HW_;
        float v[9];
#pragma unroll
        for (int dh = -1; dh <= 1; ++dh)
#pragma unroll
            for (int dw = -1; dw <= 1; ++dw) {
                int hh = h + dh, ww = w + dw;
                bool ok = (hh >= 0) & (hh < H_) & (ww >= 0) & (ww < W_);
                v[(dh + 1) * 3 + dw + 1] = ok ? xp[hh * W_ + ww] : 0.f;
            }
        const float* wc = w_off + c * KK_;
#pragma unroll
        for (int oc = 0; oc < 18; ++oc) {
            const float* wr = wc + oc * CK_;  // wave-uniform -> s_load
#pragma unroll
            for (int k = 0; k < KK_; ++k)
                acc[oc] = fmaf(v[k], wr[k], acc[oc]);
        }
    }
#pragma unroll
    for (int oc = 0; oc < 18; ++oc) partial[cg][p][oc] = acc[oc];
    __syncthreads();

    for (int e = t; e < 64 * 18; e += 512) {
        int oc = e >> 6;
        int pp = e & 63;
        float s = 0.f;
#pragma unroll
        for (int gi = 0; gi < 8; ++gi) s += partial[gi][pp][oc];
        off[((size_t)b * 18 + oc) * HW_ + pos0 + pp] = s + b_off[oc];
    }
}

// ---------------------------------------------------------------------------
// Kernel 4 (FUSED gather+GEMM), v8: 64-K stages. r2..r7 post-mortem: three
// structurally different 32-K variants all land at 79-82 us -> the wall is
// the per-stage barrier skeleton (~2600 cy/stage, ~4x its issue work), not
// LDS/L2 BW. Fix: process a kc-PAIR per stage -> 36 stages, 32 MFMA per
// stage, corner latency hidden under a 2x-longer MFMA cluster.
//   A: af[8] (2 kc x 4 frags) global->reg from the L2-resident swizzled wA,
//      double-buffered one stage ahead (reg parity). No LDS for A.
//   B: 8 uint4 corner loads at stage top -> 2x bilinear after the MFMAs ->
//      2 swizzled ds_write_b128 into s_b[2][2][2048] (parity x kc).
//   All-register loads -> compiler-exact waitcnts; only lgkmcnt(0)+barrier
//   per stage is manual. LDS 34 KB. 4 waves, wave tile 64x64, acc[4][4].
// ---------------------------------------------------------------------------
template<bool ISSUEC, bool ISSUEA, bool PROD, bool RELOAD>
__device__ __forceinline__ void fstage(
    int s, int ch0, int ch1,
    const char* xb, const char* gA0,
    __bf16 (*s_b)[2][2048],
    int (*s_id)[64][4], float (*s_w)[64][4],
    int4& id, float4& wg,
    bf16x8 (&afUse)[8], bf16x8 (&afFill)[8],
    int aoffBase,
    int n, int tc, int sc, int lid, int quad, int swz,
    f32x4 (&acc)[4][4]) {

    if (RELOAD) {                       // tables for tap (s+1)>>2 (corners
        id = *(const int4*)s_id[(s + 1) >> 2][n];   // + bilinear this stage)
        wg = *(const float4*)s_w[(s + 1) >> 2][n];
    }
    uint4 c0, c1, c2, c3, c4, c5, c6, c7;
    if (ISSUEC) {                       // corners for B(s+1), 2 kc
        const char* p0 = xb + ch0 * 64 + tc * 16;
        c0 = *(const uint4*)(p0 + id.x);
        c1 = *(const uint4*)(p0 + id.y);
        c2 = *(const uint4*)(p0 + id.z);
        c3 = *(const uint4*)(p0 + id.w);
        const char* p1 = xb + ch1 * 64 + tc * 16;
        c4 = *(const uint4*)(p1 + id.x);
        c5 = *(const uint4*)(p1 + id.y);
        c6 = *(const uint4*)(p1 + id.z);
        c7 = *(const uint4*)(p1 + id.w);
    }
    if (ISSUEA) {                       // A fragments for stage s+1 (2 kc)
        const char* ga = gA0 + (size_t)(2 * (s + 1)) * 16384 + aoffBase;
        afFill[0] = *(const bf16x8*)(ga);
        afFill[1] = *(const bf16x8*)(ga + 1024);
        afFill[2] = *(const bf16x8*)(ga + 2048);
        afFill[3] = *(const bf16x8*)(ga + 3072);
        afFill[4] = *(const bf16x8*)(ga + 16384);
        afFill[5] = *(const bf16x8*)(ga + 16384 + 1024);
        afFill[6] = *(const bf16x8*)(ga + 16384 + 2048);
        afFill[7] = *(const bf16x8*)(ga + 16384 + 3072);
    }

    __builtin_amdgcn_s_setprio(1);
#pragma unroll
    for (int j = 0; j < 2; ++j) {
        const bf16x8* pb = (const bf16x8*)s_b[s & 1][j];
        bf16x8 bv[4];
#pragma unroll
        for (int ni = 0; ni < 4; ++ni)
            bv[ni] = pb[(ni * 16 + lid) * 4 + (quad ^ swz)];
#pragma unroll
        for (int mi = 0; mi < 4; ++mi)
#pragma unroll
            for (int ni = 0; ni < 4; ++ni)
                acc[mi][ni] = __builtin_amdgcn_mfma_f32_16x16x32_bf16(
                    afUse[j * 4 + mi], bv[ni], acc[mi][ni], 0, 0, 0);
    }
    __builtin_amdgcn_s_setprio(0);

    if (PROD) {                         // B(s+1) from this stage's corners
        uint4 o0 = bilin4(c0, c1, c2, c3, wg);
        *(uint4*)((char*)s_b[(s & 1) ^ 1][0] + n * 64 + sc * 16) = o0;
        uint4 o1 = bilin4(c4, c5, c6, c7, wg);
        *(uint4*)((char*)s_b[(s & 1) ^ 1][1] + n * 64 + sc * 16) = o1;
    }
    asm volatile("s_waitcnt lgkmcnt(0)" ::: "memory");
    __builtin_amdgcn_s_barrier();
    __builtin_amdgcn_sched_barrier(0);
}

__global__ __launch_bounds__(256, 2) void k_fused(
    const unsigned short* __restrict__ xT,
    const float* __restrict__ off,
    const __bf16* __restrict__ wA,
    const float* __restrict__ b_dcn,
    float* __restrict__ out) {

    __shared__ __bf16 s_b[2][2][2048];    // 16 KB: B (parity x kc) 64n x 32k
    __shared__ int    s_id[KK_][64][4];   //  9 KB
    __shared__ float  s_w [KK_][64][4];   //  9 KB

    int bid  = blockIdx.x;                // 392 = 8 XCDs * 49
    int g    = (bid & 7) * 49 + (bid >> 3);   // image == XCD
    int b    = g / 49;
    int pos0 = (g % 49) * 64;
    int t    = threadIdx.x;
    int lane = t & 63;
    int wv   = t >> 6;                    // 4 waves, 64 M-rows each
    int lid  = lane & 15;
    int quad = lane >> 4;
    int swz  = swz4(lid);

    // --- bilinear tables (byte offsets into NHWC plane, 4 weights) ---
    for (int e = t; e < KK_ * 64; e += 256) {
        int k = e >> 6, n = e & 63;
        int pos = pos0 + n;
        int h = pos / W_, w = pos % W_;
        float dy = off[((size_t)b * 18 + 2 * k) * HW_ + pos];
        float dx = off[((size_t)b * 18 + 2 * k + 1) * HW_ + pos];
        float py = (float)(h + k / 3 - 1) + dy;
        float px = (float)(w + k % 3 - 1) + dx;
        float y0f = floorf(py), x0f = floorf(px);
        float fy = py - y0f, fx = px - x0f;
        int y0 = (int)y0f, x0 = (int)x0f;
        int y1 = y0 + 1,   x1 = x0 + 1;
        float oy0 = (y0 >= 0 && y0 < H_) ? 1.f : 0.f;
        float oy1 = (y1 >= 0 && y1 < H_) ? 1.f : 0.f;
        float ox0 = (x0 >= 0 && x0 < W_) ? 1.f : 0.f;
        float ox1 = (x1 >= 0 && x1 < W_) ? 1.f : 0.f;
        int y0c = min(max(y0, 0), H_ - 1), y1c = min(max(y1, 0), H_ - 1);
        int x0c = min(max(x0, 0), W_ - 1), x1c = min(max(x1, 0), W_ - 1);
        s_id[k][n][0] = (y0c * W_ + x0c) * 512;   // 256 ch * 2 B
        s_id[k][n][1] = (y0c * W_ + x1c) * 512;
        s_id[k][n][2] = (y1c * W_ + x0c) * 512;
        s_id[k][n][3] = (y1c * W_ + x1c) * 512;
        s_w[k][n][0] = (1.f - fy) * (1.f - fx) * oy0 * ox0;
        s_w[k][n][1] = (1.f - fy) * fx         * oy0 * ox1;
        s_w[k][n][2] = fy * (1.f - fx)         * oy1 * ox0;
        s_w[k][n][3] = fy * fx                 * oy1 * ox1;
    }
    __syncthreads();

    int n  = t >> 2;                      // 64 positions
    int tc = t & 3;                       // 16B chunk within 64B k-row
    int sc = tc ^ swz4(n);
    const char* xb  = (const char*)(xT + (size_t)b * HW_ * 256);
    const char* gA0 = (const char*)wA;
    // per-lane A-fragment byte offset within a kc-slice (16 KB):
    int aoffBase = (wv * 64 + lid) * 64 + (quad ^ swz) * 16;

    f32x4 acc[4][4];
#pragma unroll
    for (int mi = 0; mi < 4; ++mi)
#pragma unroll
        for (int ni = 0; ni < 4; ++ni)
            acc[mi][ni] = (f32x4)(0.f);

    int4   id = *(const int4*)s_id[0][n];
    float4 wg = *(const float4*)s_w[0][n];
    bf16x8 afA[8], afB[8];

    // ---- prologue: B(0) (kc 0,1) built in-reg; af(stage 0) loaded ----
    {
        const char* p0 = xb + tc * 16;            // ch-block 0
        uint4 c0 = *(const uint4*)(p0 + id.x);
        uint4 c1 = *(const uint4*)(p0 + id.y);
        uint4 c2 = *(const uint4*)(p0 + id.z);
        uint4 c3 = *(const uint4*)(p0 + id.w);
        const char* p1 = xb + 64 + tc * 16;       // ch-block 1
        uint4 c4 = *(const uint4*)(p1 + id.x);
        uint4 c5 = *(const uint4*)(p1 + id.y);
        uint4 c6 = *(const uint4*)(p1 + id.z);
        uint4 c7 = *(const uint4*)(p1 + id.w);
        const char* ga = gA0 + aoffBase;          // af(stage 0): kc 0,1
        afA[0] = *(const bf16x8*)(ga);
        afA[1] = *(const bf16x8*)(ga + 1024);
        afA[2] = *(const bf16x8*)(ga + 2048);
        afA[3] = *(const bf16x8*)(ga + 3072);
        afA[4] = *(const bf16x8*)(ga + 16384);
        afA[5] = *(const bf16x8*)(ga + 16384 + 1024);
        afA[6] = *(const bf16x8*)(ga + 16384 + 2048);
        afA[7] = *(const bf16x8*)(ga + 16384 + 3072);
        uint4 o0 = bilin4(c0, c1, c2, c3, wg);
        *(uint4*)((char*)s_b[0][0] + n * 64 + sc * 16) = o0;
        uint4 o1 = bilin4(c4, c5, c6, c7, wg);
        *(uint4*)((char*)s_b[0][1] + n * 64 + sc * 16) = o1;
    }
    asm volatile("s_waitcnt lgkmcnt(0)" ::: "memory");
    __builtin_amdgcn_s_barrier();
    __builtin_amdgcn_sched_barrier(0);

    // ---- main: 8 full tap-blocks of 4 stages (s = 0..31) ----
    // stage s covers kc {2s, 2s+1}; corners for B(s+1) use ch (2s+2)&7,
    // (2s+3)&7 -> within a tap block: (2,3) (4,5) (6,7) (0,1 next tap).
    for (int tap = 0; tap < 8; ++tap) {
        int s0 = tap * 4;
        fstage<true, true, true, false>(s0 + 0, 2, 3, xb, gA0, s_b, s_id, s_w, id, wg, afA, afB, aoffBase, n, tc, sc, lid, quad, swz, acc);
        fstage<true, true, true, false>(s0 + 1, 4, 5, xb, gA0, s_b, s_id, s_w, id, wg, afB, afA, aoffBase, n, tc, sc, lid, quad, swz, acc);
        fstage<true, true, true, false>(s0 + 2, 6, 7, xb, gA0, s_b, s_id, s_w, id, wg, afA, afB, aoffBase, n, tc, sc, lid, quad, swz, acc);
        fstage<true, true, true, true >(s0 + 3, 0, 1, xb, gA0, s_b, s_id, s_w, id, wg, afB, afA, aoffBase, n, tc, sc, lid, quad, swz, acc);
    }
    // ---- tail tap-block (s = 32..35, tap 8) ----
    fstage<true,  true,  true,  false>(32, 2, 3, xb, gA0, s_b, s_id, s_w, id, wg, afA, afB, aoffBase, n, tc, sc, lid, quad, swz, acc);
    fstage<true,  true,  true,  false>(33, 4, 5, xb, gA0, s_b, s_id, s_w, id, wg, afB, afA, aoffBase, n, tc, sc, lid, quad, swz, acc);
    fstage<true,  true,  true,  false>(34, 6, 7, xb, gA0, s_b, s_id, s_w, id, wg, afA, afB, aoffBase, n, tc, sc, lid, quad, swz, acc);
    fstage<false, false, false, false>(35, 0, 0, xb, gA0, s_b, s_id, s_w, id, wg, afB, afA, aoffBase, n, tc, sc, lid, quad, swz, acc);

    // ---- epilogue: bias + store. D: col(n)=lane&15, row(m)=quad*4+reg ----
#pragma unroll
    for (int mi = 0; mi < 4; ++mi) {
#pragma unroll
        for (int r = 0; r < 4; ++r) {
            int m = wv * 64 + mi * 16 + quad * 4 + r;
            float bias = b_dcn[m];
            float* po = out + ((size_t)b * O_ + m) * HW_ + pos0 + lid;
#pragma unroll
            for (int ni = 0; ni < 4; ++ni)
                po[ni * 16] = acc[mi][ni][r] + bias;
        }
    }
}

extern "C" void kernel_launch(void* const* d_in, const int* in_sizes, int n_in,
                              void* d_out, int out_size, void* d_ws, size_t ws_size,
                              hipStream_t stream) {
    const float* x     = (const float*)d_in[0];
    const float* w_off = (const float*)d_in[1];
    const float* b_off = (const float*)d_in[2];
    const float* w_dcn = (const float*)d_in[3];
    const float* b_dcn = (const float*)d_in[4];
    float* out = (float*)d_out;

    // ws: off 1.81 | wA 1.18 | xT 12.85 MB (part eliminated)
    const size_t offBytes  = (size_t)451584 * 4;
    const size_t wABytes   = (size_t)589824 * 2;
    float*          off  = (float*)d_ws;
    unsigned short* wA   = (unsigned short*)((char*)d_ws + offBytes);
    unsigned short* xT   = (unsigned short*)((char*)d_ws + offBytes + wABytes);

    k_buildA <<<2304, 256, 0, stream>>>(w_dcn, wA);
    k_transx <<<1568, 256, 0, stream>>>(x, xT);
    k_offc   <<<392,  512, 0, stream>>>(x, w_off, b_off, off);
    k_fused  <<<392,  256, 0, stream>>>(xT, off, (const __bf16*)wA, b_dcn, out);
}

// Round 10
// 184.041 us; speedup vs baseline: 1.1821x; 1.0450x over previous
//
#include <hip/hip_runtime.h>

#define B_  8
#define C_  256
#define O_  256
#define H_  56
#define W_  56
#define HW_ 3136
#define KK_ 9
#define CK_ 2304   // C_*KK_
#define NKC 72     // K-chunks of 32

typedef __bf16    bf16x8 __attribute__((ext_vector_type(8)));
typedef float     f32x4  __attribute__((ext_vector_type(4)));

// XOR chunk swizzle: logical 16B-chunk q of row r stored at q ^ swz4(r).
__device__ __forceinline__ int swz4(int r) { return (r & 3) ^ ((r >> 2) & 3); }

__device__ __forceinline__ float blo(unsigned u) {
    return __builtin_bit_cast(float, u << 16);
}
__device__ __forceinline__ float bhi(unsigned u) {
    return __builtin_bit_cast(float, u & 0xffff0000u);
}
__device__ __forceinline__ unsigned pkbf(float lo, float hi) {
    unsigned short a = __builtin_bit_cast(unsigned short, (__bf16)lo);
    unsigned short b = __builtin_bit_cast(unsigned short, (__bf16)hi);
    return (unsigned)a | ((unsigned)b << 16);
}

__device__ __forceinline__ uint4 bilin4(uint4 c00, uint4 c01, uint4 c10, uint4 c11,
                                        float4 wg) {
    uint4 o;
    float lo_, hi_;
    lo_ = wg.x*blo(c00.x) + wg.y*blo(c01.x) + wg.z*blo(c10.x) + wg.w*blo(c11.x);
    hi_ = wg.x*bhi(c00.x) + wg.y*bhi(c01.x) + wg.z*bhi(c10.x) + wg.w*bhi(c11.x);
    o.x = pkbf(lo_, hi_);
    lo_ = wg.x*blo(c00.y) + wg.y*blo(c01.y) + wg.z*blo(c10.y) + wg.w*blo(c11.y);
    hi_ = wg.x*bhi(c00.y) + wg.y*bhi(c01.y) + wg.z*bhi(c10.y) + wg.w*bhi(c11.y);
    o.y = pkbf(lo_, hi_);
    lo_ = wg.x*blo(c00.z) + wg.y*blo(c01.z) + wg.z*blo(c10.z) + wg.w*blo(c11.z);
    hi_ = wg.x*bhi(c00.z) + wg.y*bhi(c01.z) + wg.z*bhi(c10.z) + wg.w*bhi(c11.z);
    o.z = pkbf(lo_, hi_);
    lo_ = wg.x*blo(c00.w) + wg.y*blo(c01.w) + wg.z*blo(c10.w) + wg.w*blo(c11.w);
    hi_ = wg.x*bhi(c00.w) + wg.y*bhi(c01.w) + wg.z*bhi(c10.w) + wg.w*bhi(c11.w);
    o.w = pkbf(lo_, hi_);
    return o;
}

// ---------------------------------------------------------------------------
// Kernel 1: wA[kc][m=256][32] bf16, tap-major K (gk=kc*32+kl -> tap=gk>>8,
// c=gk&255), XOR chunk swizzle baked into the global image. 1.18 MB.
// ---------------------------------------------------------------------------
__global__ __launch_bounds__(256) void k_buildA(const float* __restrict__ w,
                                                unsigned short* __restrict__ wA) {
    int d  = blockIdx.x * 256 + threadIdx.x;   // exact 2304*256
    int kc = d >> 13;
    int rd = d & 8191;
    int m  = rd >> 5;
    int pos = rd & 31;
    int q  = (pos >> 3) ^ swz4(m);
    int kl = q * 8 + (pos & 7);
    int gk = kc * 32 + kl;
    int tap = gk >> 8, c = gk & 255;
    __bf16 v = (__bf16)w[m * CK_ + c * KK_ + tap];
    wA[d] = __builtin_bit_cast(unsigned short, v);
}

// ---------------------------------------------------------------------------
// Kernel 1b: wT[c][tap][20] fp32, oc-contiguous (pads zeroed) for the
// offset conv's LDS broadcast reads. 184 KB.
// ---------------------------------------------------------------------------
__global__ __launch_bounds__(256) void k_buildW(const float* __restrict__ w_off,
                                                float* __restrict__ wT) {
    int i = blockIdx.x * 256 + threadIdx.x;    // exact 256*9*20 = 46080
    int c  = i / 180;
    int r  = i % 180;
    int k  = r / 20;
    int oc = r % 20;
    wT[i] = (oc < 18) ? w_off[oc * CK_ + c * KK_ + k] : 0.f;
}

// ---------------------------------------------------------------------------
// Kernel 2: x NCHW f32 -> xT NHWC bf16 (12.85 MB).
// ---------------------------------------------------------------------------
__global__ __launch_bounds__(256) void k_transx(const float* __restrict__ x,
                                                unsigned short* __restrict__ xT) {
    __shared__ float s[64][65];
    int bt   = blockIdx.x;            // 8 * 49 * 4
    int c64  = bt & 3;
    int hw64 = (bt >> 2) % 49;
    int b    = bt / 196;
    int tx = threadIdx.x & 63;
    int ty = threadIdx.x >> 6;
#pragma unroll
    for (int i = 0; i < 16; ++i)
        s[i * 4 + ty][tx] =
            x[((size_t)(b * 256 + c64 * 64 + i * 4 + ty)) * HW_ + hw64 * 64 + tx];
    __syncthreads();
#pragma unroll
    for (int i = 0; i < 16; ++i) {
        float v = s[tx][i * 4 + ty];
        xT[((size_t)b * HW_ + hw64 * 64 + i * 4 + ty) * 256 + c64 * 64 + tx] =
            __builtin_bit_cast(unsigned short, (__bf16)v);
    }
}

// ---------------------------------------------------------------------------
// Kernel 3 (offset conv, v2): weights via LDS broadcast instead of s_load.
// r8 post-mortem: 162 wave-uniform s_loads/channel overflowed the SGPR
// budget -> serialized batches at scalar-cache latency (VALUBusy 22%).
// Now: 4 phases of 64 ch; phase weights (46 KB, [ch][tap][20] oc-rows)
// cooperatively staged to LDS; per channel 45 broadcast ds_read_b128
// interleave with 162 FMAs. LDS reused for the partial-reduce buffer.
// Grid 392 (XCD-image swizzle), 512 thr = 64 pos x 8 ch-groups.
// ---------------------------------------------------------------------------
__global__ __launch_bounds__(512) void k_offc(const float* __restrict__ x,
                                              const float* __restrict__ wT,
                                              const float* __restrict__ b_off,
                                              float* __restrict__ off) {
    __shared__ float4 smem4[2880];            // 46080 B (wlds | partial)
    int t  = threadIdx.x;
    int p  = t & 63;
    int cg = __builtin_amdgcn_readfirstlane(t >> 6);
    int bid  = blockIdx.x;                    // 392 = 8 XCDs * 49
    int g    = (bid & 7) * 49 + (bid >> 3);
    int b    = g / 49;
    int pos0 = (g % 49) * 64;
    int pos  = pos0 + p;
    int h = pos / W_;
    int w = pos % W_;
    const float* xb = x + (size_t)b * C_ * HW_;
    const float4* wTg = (const float4*)wT;
    float* sp = (float*)smem4;

    float acc[18];
#pragma unroll
    for (int i = 0; i < 18; ++i) acc[i] = 0.f;

    for (int ph = 0; ph < 4; ++ph) {
        __syncthreads();                      // wlds safe to overwrite
        for (int e = t; e < 2880; e += 512)   // stage 64ch x 9tap x 20oc
            smem4[e] = wTg[ph * 2880 + e];
        __syncthreads();

        for (int cc = 0; cc < 8; ++cc) {
            int c = ph * 64 + cg * 8 + cc;
            const float* xp = xb + c * HW_;
            float v[9];
#pragma unroll
            for (int dh = -1; dh <= 1; ++dh)
#pragma unroll
                for (int dw = -1; dw <= 1; ++dw) {
                    int hh = h + dh, ww = w + dw;
                    bool ok = (hh >= 0) & (hh < H_) & (ww >= 0) & (ww < W_);
                    v[(dh + 1) * 3 + dw + 1] = ok ? xp[hh * W_ + ww] : 0.f;
                }
            const float* wr = sp + (cg * 8 + cc) * 180;  // [tap][20]
#pragma unroll
            for (int k = 0; k < KK_; ++k) {
                float4 w0 = *(const float4*)(wr + k * 20 + 0);
                float4 w1 = *(const float4*)(wr + k * 20 + 4);
                float4 w2 = *(const float4*)(wr + k * 20 + 8);
                float4 w3 = *(const float4*)(wr + k * 20 + 12);
                float4 w4 = *(const float4*)(wr + k * 20 + 16);
                float vk = v[k];
                acc[0]  = fmaf(vk, w0.x, acc[0]);
                acc[1]  = fmaf(vk, w0.y, acc[1]);
                acc[2]  = fmaf(vk, w0.z, acc[2]);
                acc[3]  = fmaf(vk, w0.w, acc[3]);
                acc[4]  = fmaf(vk, w1.x, acc[4]);
                acc[5]  = fmaf(vk, w1.y, acc[5]);
                acc[6]  = fmaf(vk, w1.z, acc[6]);
                acc[7]  = fmaf(vk, w1.w, acc[7]);
                acc[8]  = fmaf(vk, w2.x, acc[8]);
                acc[9]  = fmaf(vk, w2.y, acc[9]);
                acc[10] = fmaf(vk, w2.z, acc[10]);
                acc[11] = fmaf(vk, w2.w, acc[11]);
                acc[12] = fmaf(vk, w3.x, acc[12]);
                acc[13] = fmaf(vk, w3.y, acc[13]);
                acc[14] = fmaf(vk, w3.z, acc[14]);
                acc[15] = fmaf(vk, w3.w, acc[15]);
                acc[16] = fmaf(vk, w4.x, acc[16]);
                acc[17] = fmaf(vk, w4.y, acc[17]);
            }
        }
    }

    __syncthreads();                          // wlds dead -> reuse as partial
#pragma unroll
    for (int oc = 0; oc < 18; ++oc) sp[(cg * 64 + p) * 18 + oc] = acc[oc];
    __syncthreads();

    for (int e = t; e < 64 * 18; e += 512) {
        int oc = e >> 6;
        int pp = e & 63;
        float s = 0.f;
#pragma unroll
        for (int gi = 0; gi < 8; ++gi) s += sp[(gi * 64 + pp) * 18 + oc];
        off[((size_t)b * 18 + oc) * HW_ + pos0 + pp] = s + b_off[oc];
    }
}

// ---------------------------------------------------------------------------
// Kernel 4 (FUSED gather+GEMM), v8 (UNCHANGED from round 8, verified):
// 64-K stages, A global->reg double-buffered, B produced in-kernel.
// ---------------------------------------------------------------------------
template<bool ISSUEC, bool ISSUEA, bool PROD, bool RELOAD>
__device__ __forceinline__ void fstage(
    int s, int ch0, int ch1,
    const char* xb, const char* gA0,
    __bf16 (*s_b)[2][2048],
    int (*s_id)[64][4], float (*s_w)[64][4],
    int4& id, float4& wg,
    bf16x8 (&afUse)[8], bf16x8 (&afFill)[8],
    int aoffBase,
    int n, int tc, int sc, int lid, int quad, int swz,
    f32x4 (&acc)[4][4]) {

    if (RELOAD) {                       // tables for tap (s+1)>>2
        id = *(const int4*)s_id[(s + 1) >> 2][n];
        wg = *(const float4*)s_w[(s + 1) >> 2][n];
    }
    uint4 c0, c1, c2, c3, c4, c5, c6, c7;
    if (ISSUEC) {                       // corners for B(s+1), 2 kc
        const char* p0 = xb + ch0 * 64 + tc * 16;
        c0 = *(const uint4*)(p0 + id.x);
        c1 = *(const uint4*)(p0 + id.y);
        c2 = *(const uint4*)(p0 + id.z);
        c3 = *(const uint4*)(p0 + id.w);
        const char* p1 = xb + ch1 * 64 + tc * 16;
        c4 = *(const uint4*)(p1 + id.x);
        c5 = *(const uint4*)(p1 + id.y);
        c6 = *(const uint4*)(p1 + id.z);
        c7 = *(const uint4*)(p1 + id.w);
    }
    if (ISSUEA) {                       // A fragments for stage s+1 (2 kc)
        const char* ga = gA0 + (size_t)(2 * (s + 1)) * 16384 + aoffBase;
        afFill[0] = *(const bf16x8*)(ga);
        afFill[1] = *(const bf16x8*)(ga + 1024);
        afFill[2] = *(const bf16x8*)(ga + 2048);
        afFill[3] = *(const bf16x8*)(ga + 3072);
        afFill[4] = *(const bf16x8*)(ga + 16384);
        afFill[5] = *(const bf16x8*)(ga + 16384 + 1024);
        afFill[6] = *(const bf16x8*)(ga + 16384 + 2048);
        afFill[7] = *(const bf16x8*)(ga + 16384 + 3072);
    }

    __builtin_amdgcn_s_setprio(1);
#pragma unroll
    for (int j = 0; j < 2; ++j) {
        const bf16x8* pb = (const bf16x8*)s_b[s & 1][j];
        bf16x8 bv[4];
#pragma unroll
        for (int ni = 0; ni < 4; ++ni)
            bv[ni] = pb[(ni * 16 + lid) * 4 + (quad ^ swz)];
#pragma unroll
        for (int mi = 0; mi < 4; ++mi)
#pragma unroll
            for (int ni = 0; ni < 4; ++ni)
                acc[mi][ni] = __builtin_amdgcn_mfma_f32_16x16x32_bf16(
                    afUse[j * 4 + mi], bv[ni], acc[mi][ni], 0, 0, 0);
    }
    __builtin_amdgcn_s_setprio(0);

    if (PROD) {                         // B(s+1) from this stage's corners
        uint4 o0 = bilin4(c0, c1, c2, c3, wg);
        *(uint4*)((char*)s_b[(s & 1) ^ 1][0] + n * 64 + sc * 16) = o0;
        uint4 o1 = bilin4(c4, c5, c6, c7, wg);
        *(uint4*)((char*)s_b[(s & 1) ^ 1][1] + n * 64 + sc * 16) = o1;
    }
    asm volatile("s_waitcnt lgkmcnt(0)" ::: "memory");
    __builtin_amdgcn_s_barrier();
    __builtin_amdgcn_sched_barrier(0);
}

__global__ __launch_bounds__(256, 2) void k_fused(
    const unsigned short* __restrict__ xT,
    const float* __restrict__ off,
    const __bf16* __restrict__ wA,
    const float* __restrict__ b_dcn,
    float* __restrict__ out) {

    __shared__ __bf16 s_b[2][2][2048];    // 16 KB: B (parity x kc) 64n x 32k
    __shared__ int    s_id[KK_][64][4];   //  9 KB
    __shared__ float  s_w [KK_][64][4];   //  9 KB

    int bid  = blockIdx.x;                // 392 = 8 XCDs * 49
    int g    = (bid & 7) * 49 + (bid >> 3);   // image == XCD
    int b    = g / 49;
    int pos0 = (g % 49) * 64;
    int t    = threadIdx.x;
    int lane = t & 63;
    int wv   = t >> 6;                    // 4 waves, 64 M-rows each
    int lid  = lane & 15;
    int quad = lane >> 4;
    int swz  = swz4(lid);

    // --- bilinear tables (byte offsets into NHWC plane, 4 weights) ---
    for (int e = t; e < KK_ * 64; e += 256) {
        int k = e >> 6, n = e & 63;
        int pos = pos0 + n;
        int h = pos / W_, w = pos % W_;
        float dy = off[((size_t)b * 18 + 2 * k) * HW_ + pos];
        float dx = off[((size_t)b * 18 + 2 * k + 1) * HW_ + pos];
        float py = (float)(h + k / 3 - 1) + dy;
        float px = (float)(w + k % 3 - 1) + dx;
        float y0f = floorf(py), x0f = floorf(px);
        float fy = py - y0f, fx = px - x0f;
        int y0 = (int)y0f, x0 = (int)x0f;
        int y1 = y0 + 1,   x1 = x0 + 1;
        float oy0 = (y0 >= 0 && y0 < H_) ? 1.f : 0.f;
        float oy1 = (y1 >= 0 && y1 < H_) ? 1.f : 0.f;
        float ox0 = (x0 >= 0 && x0 < W_) ? 1.f : 0.f;
        float ox1 = (x1 >= 0 && x1 < W_) ? 1.f : 0.f;
        int y0c = min(max(y0, 0), H_ - 1), y1c = min(max(y1, 0), H_ - 1);
        int x0c = min(max(x0, 0), W_ - 1), x1c = min(max(x1, 0), W_ - 1);
        s_id[k][n][0] = (y0c * W_ + x0c) * 512;   // 256 ch * 2 B
        s_id[k][n][1] = (y0c * W_ + x1c) * 512;
        s_id[k][n][2] = (y1c * W_ + x0c) * 512;
        s_id[k][n][3] = (y1c * W_ + x1c) * 512;
        s_w[k][n][0] = (1.f - fy) * (1.f - fx) * oy0 * ox0;
        s_w[k][n][1] = (1.f - fy) * fx         * oy0 * ox1;
        s_w[k][n][2] = fy * (1.f - fx)         * oy1 * ox0;
        s_w[k][n][3] = fy * fx                 * oy1 * ox1;
    }
    __syncthreads();

    int n  = t >> 2;                      // 64 positions
    int tc = t & 3;                       // 16B chunk within 64B k-row
    int sc = tc ^ swz4(n);
    const char* xb  = (const char*)(xT + (size_t)b * HW_ * 256);
    const char* gA0 = (const char*)wA;
    int aoffBase = (wv * 64 + lid) * 64 + (quad ^ swz) * 16;

    f32x4 acc[4][4];
#pragma unroll
    for (int mi = 0; mi < 4; ++mi)
#pragma unroll
        for (int ni = 0; ni < 4; ++ni)
            acc[mi][ni] = (f32x4)(0.f);

    int4   id = *(const int4*)s_id[0][n];
    float4 wg = *(const float4*)s_w[0][n];
    bf16x8 afA[8], afB[8];

    // ---- prologue: B(0) (kc 0,1) built in-reg; af(stage 0) loaded ----
    {
        const char* p0 = xb + tc * 16;            // ch-block 0
        uint4 c0 = *(const uint4*)(p0 + id.x);
        uint4 c1 = *(const uint4*)(p0 + id.y);
        uint4 c2 = *(const uint4*)(p0 + id.z);
        uint4 c3 = *(const uint4*)(p0 + id.w);
        const char* p1 = xb + 64 + tc * 16;       // ch-block 1
        uint4 c4 = *(const uint4*)(p1 + id.x);
        uint4 c5 = *(const uint4*)(p1 + id.y);
        uint4 c6 = *(const uint4*)(p1 + id.z);
        uint4 c7 = *(const uint4*)(p1 + id.w);
        const char* ga = gA0 + aoffBase;          // af(stage 0): kc 0,1
        afA[0] = *(const bf16x8*)(ga);
        afA[1] = *(const bf16x8*)(ga + 1024);
        afA[2] = *(const bf16x8*)(ga + 2048);
        afA[3] = *(const bf16x8*)(ga + 3072);
        afA[4] = *(const bf16x8*)(ga + 16384);
        afA[5] = *(const bf16x8*)(ga + 16384 + 1024);
        afA[6] = *(const bf16x8*)(ga + 16384 + 2048);
        afA[7] = *(const bf16x8*)(ga + 16384 + 3072);
        uint4 o0 = bilin4(c0, c1, c2, c3, wg);
        *(uint4*)((char*)s_b[0][0] + n * 64 + sc * 16) = o0;
        uint4 o1 = bilin4(c4, c5, c6, c7, wg);
        *(uint4*)((char*)s_b[0][1] + n * 64 + sc * 16) = o1;
    }
    asm volatile("s_waitcnt lgkmcnt(0)" ::: "memory");
    __builtin_amdgcn_s_barrier();
    __builtin_amdgcn_sched_barrier(0);

    // ---- main: 8 full tap-blocks of 4 stages (s = 0..31) ----
    for (int tap = 0; tap < 8; ++tap) {
        int s0 = tap * 4;
        fstage<true, true, true, false>(s0 + 0, 2, 3, xb, gA0, s_b, s_id, s_w, id, wg, afA, afB, aoffBase, n, tc, sc, lid, quad, swz, acc);
        fstage<true, true, true, false>(s0 + 1, 4, 5, xb, gA0, s_b, s_id, s_w, id, wg, afB, afA, aoffBase, n, tc, sc, lid, quad, swz, acc);
        fstage<true, true, true, false>(s0 + 2, 6, 7, xb, gA0, s_b, s_id, s_w, id, wg, afA, afB, aoffBase, n, tc, sc, lid, quad, swz, acc);
        fstage<true, true, true, true >(s0 + 3, 0, 1, xb, gA0, s_b, s_id, s_w, id, wg, afB, afA, aoffBase, n, tc, sc, lid, quad, swz, acc);
    }
    // ---- tail tap-block (s = 32..35, tap 8) ----
    fstage<true,  true,  true,  false>(32, 2, 3, xb, gA0, s_b, s_id, s_w, id, wg, afA, afB, aoffBase, n, tc, sc, lid, quad, swz, acc);
    fstage<true,  true,  true,  false>(33, 4, 5, xb, gA0, s_b, s_id, s_w, id, wg, afB, afA, aoffBase, n, tc, sc, lid, quad, swz, acc);
    fstage<true,  true,  true,  false>(34, 6, 7, xb, gA0, s_b, s_id, s_w, id, wg, afA, afB, aoffBase, n, tc, sc, lid, quad, swz, acc);
    fstage<false, false, false, false>(35, 0, 0, xb, gA0, s_b, s_id, s_w, id, wg, afB, afA, aoffBase, n, tc, sc, lid, quad, swz, acc);

    // ---- epilogue: bias + store. D: col(n)=lane&15, row(m)=quad*4+reg ----
#pragma unroll
    for (int mi = 0; mi < 4; ++mi) {
#pragma unroll
        for (int r = 0; r < 4; ++r) {
            int m = wv * 64 + mi * 16 + quad * 4 + r;
            float bias = b_dcn[m];
            float* po = out + ((size_t)b * O_ + m) * HW_ + pos0 + lid;
#pragma unroll
            for (int ni = 0; ni < 4; ++ni)
                po[ni * 16] = acc[mi][ni][r] + bias;
        }
    }
}

extern "C" void kernel_launch(void* const* d_in, const int* in_sizes, int n_in,
                              void* d_out, int out_size, void* d_ws, size_t ws_size,
                              hipStream_t stream) {
    const float* x     = (const float*)d_in[0];
    const float* w_off = (const float*)d_in[1];
    const float* b_off = (const float*)d_in[2];
    const float* w_dcn = (const float*)d_in[3];
    const float* b_dcn = (const float*)d_in[4];
    float* out = (float*)d_out;

    // ws: off 1.81 | wA 1.18 | xT 12.85 | wT 0.18 MB
    const size_t offBytes  = (size_t)451584 * 4;
    const size_t wABytes   = (size_t)589824 * 2;
    const size_t xTBytes   = (size_t)B_ * HW_ * 256 * 2;
    float*          off  = (float*)d_ws;
    unsigned short* wA   = (unsigned short*)((char*)d_ws + offBytes);
    unsigned short* xT   = (unsigned short*)((char*)d_ws + offBytes + wABytes);
    float*          wT   = (float*)((char*)d_ws + offBytes + wABytes + xTBytes);

    k_buildA <<<2304, 256, 0, stream>>>(w_dcn, wA);
    k_buildW <<<180,  256, 0, stream>>>(w_off, wT);
    k_transx <<<1568, 256, 0, stream>>>(x, xT);
    k_offc   <<<392,  512, 0, stream>>>(x, wT, b_off, off);
    k_fused  <<<392,  256, 0, stream>>>(xT, off, (const __bf16*)wA, b_dcn, out);
}